// Round 13
// baseline (15053.252 us; speedup 1.0000x reference)
//
#include <hip/hip_runtime.h>

#define NHID 1024
#define NB   128
#define NIN  64
#define TSTEPS 512
#define NBLK 128
#define NTHR 512
#define GROW 8                  // batch rows per group
#define BCOL 128                // hidden cols per block
#define SLOTN (NB * NHID)       // elements per exchange slot

typedef __attribute__((ext_vector_type(8))) short short8v;
typedef __attribute__((ext_vector_type(4))) float f32x4;
typedef __attribute__((ext_vector_type(4))) unsigned u32x4;

__device__ __forceinline__ short8v ld8(const unsigned short* p) {
  return *reinterpret_cast<const short8v*>(p);
}

__device__ __forceinline__ unsigned short f2b(float x) {
  union { float f; unsigned u; } v; v.f = x;
  unsigned r = v.u + 0x7fffu + ((v.u >> 16) & 1u);
  return (unsigned short)(r >> 16);
}

// Agent-scope 2B atomic store for exchange data — R8-proven flavor.
// (R9/R10/R11 A/B'd 16B sc1 / 16B sc0sc1 / all-2B-poison: all regressed.)
__device__ __forceinline__ void cstore16(unsigned short* p, unsigned short v) {
  __hip_atomic_store(p, v, __ATOMIC_RELAXED, __HIP_MEMORY_SCOPE_AGENT);
}

// Unit validity: poison 0xFFFF is unforgeable (|h|,|s| < 1 strictly).
__device__ __forceinline__ bool ok16(u32x4 v) {
  unsigned bad = 0;
#pragma unroll
  for (int i = 0; i < 4; ++i) {
    bad |= (unsigned)((v[i] & 0xFFFFu) == 0xFFFFu);
    bad |= (unsigned)((v[i] >> 16) == 0xFFFFu);
  }
  return bad == 0;
}

struct GruParams {
  const unsigned short* u;                    // [T][B][NIN] bf16
  const unsigned short* WhzT; const unsigned short* WhrT; const unsigned short* WhhT; // [n][k]
  const unsigned short* WuzT; const unsigned short* WurT; const unsigned short* WuhT; // [n][k]
  const float* bz; const float* br; const float* bh;
  float* h;                                   // [B][NHID] f32 — final h only
  unsigned short* hb;                         // [4][B][NHID] bf16 h slots (poison-synced)
  unsigned short* sb;                         // [4][B][NHID] bf16 r*h slots (poison-synced)
};

// Block = 8 batch rows (rg of 16) x 128 hidden cols (cgB of 8); 8 waves, each
// wave = 16 cols x FULL K=1024. The wave's MFMA acc IS the finished gate
// pre-activation: no K-half reduction, no red[] LDS, no cross-wave handoff,
// ONE barrier per phase. Groups of 8 blocks rendezvous via poisoned data.
__global__ __launch_bounds__(NTHR, 2) void gru_main(GruParams p) {
  __shared__ unsigned short stage[GROW * NHID];  // 16KB staged h/s rows (swizzled)

  const int tid  = threadIdx.x;
  const int lane = tid & 63;
  const int w    = tid >> 6;          // wave id 0..7 -> col tile
  const int rg   = blockIdx.x >> 3;   // 16 row groups (8 rows each)
  const int cgB  = blockIdx.x & 7;    // 8 col blocks (128 cols each)
  const int lr   = lane & 15;
  const int ar_  = lr & 7;            // aliased A-row for 8-row tiles
  const int lk   = (lane >> 4) * 8;

  const int colN = cgB * BCOL + w * 16 + lr;     // this lane's output col
  const unsigned short* wz  = p.WhzT + (size_t)colN * NHID + lk;
  const unsigned short* wr  = p.WhrT + (size_t)colN * NHID + lk;
  const unsigned short* wh  = p.WhhT + (size_t)colN * NHID + lk;
  const unsigned short* wuz = p.WuzT + colN * NIN + lk;
  const unsigned short* wur = p.WurT + colN * NIN + lk;
  const unsigned short* wuh = p.WuhT + colN * NIN + lk;

  const int orow0 = (lane >> 4) * 4;  // D rows (lane>>4)*4+i; real rows < 8
  const bool owner = orow0 < GROW;    // lanes 0..31
  const float bzv = p.bz[colN];
  const float brv = p.br[colN];
  const float bhv = p.bh[colN];

  const u32x4 poisonv = {0xFFFFFFFFu, 0xFFFFFFFFu, 0xFFFFFFFFu, 0xFFFFFFFFu};

  float h_own[4] = {0.f, 0.f, 0.f, 0.f};
  float zreg[4];

  // Poll-stage: 8 rows x 1024 cols = 1024 16B units; 512 thr x 2 units.
  // 16B sc0sc1 loads until non-poison (tearing-safe), then swizzled LDS write.
#define PSTAGE(SRC)                                                              \
  {                                                                              \
    int j0 = tid, j1 = tid + NTHR;                                               \
    const void* g0 = (SRC) + (j0 >> 7) * NHID + (j0 & 127) * 8;                  \
    const void* g1 = (SRC) + (j1 >> 7) * NHID + (j1 & 127) * 8;                  \
    char* d0 = (char*)stage +                                                    \
               (((j0 >> 7) * 2048) | (((j0 & 127) * 16) ^ (((j0 >> 7) & 7) << 4)));\
    char* d1 = (char*)stage +                                                    \
               (((j1 >> 7) * 2048) | (((j1 & 127) * 16) ^ (((j1 >> 7) & 7) << 4)));\
    u32x4 v0 = poisonv, v1 = poisonv;                                            \
    bool k0 = false, k1 = false;                                                 \
    for (int spin = 0; spin < (1 << 13); ++spin) {                               \
      if (!k0) asm volatile("global_load_dwordx4 %0, %1, off sc0 sc1"            \
                            : "=v"(v0) : "v"(g0) : "memory");                    \
      if (!k1) asm volatile("global_load_dwordx4 %0, %1, off sc0 sc1"            \
                            : "=v"(v1) : "v"(g1) : "memory");                    \
      asm volatile("s_waitcnt vmcnt(0)" ::: "memory");                           \
      k0 = k0 || ok16(v0);                                                       \
      k1 = k1 || ok16(v1);                                                       \
      if (k0 && k1) break;                                                       \
    }                                                                            \
    *(u32x4*)d0 = v0;                                                            \
    *(u32x4*)d1 = v1;                                                            \
  }

  // Re-poison own 128-col slice (8 rows) of a consumed slot: 128 x 16B units.
  // Issue-only; drains at the NEXT phase's PSTAGE vmcnt(0) (3-step slack).
#define REPOISON(SLOTSLICE)                                                      \
  if (tid < 128) {                                                               \
    void* rp = (SLOTSLICE) + (tid >> 4) * NHID + cgB * BCOL + (tid & 15) * 8;    \
    asm volatile("global_store_dwordx4 %0, %1, off sc0 sc1"                      \
                 :: "v"(rp), "v"(poisonv) : "memory");                           \
  }

#define LDSA(IT)                                                                \
  (*(const short8v*)((const char*)stage +                                       \
     ((ar_ * 2048) | ((((IT) * 32 + lk) * 2) ^ (ar_ << 4)))))

  for (int t = 0; t < TSTEPS; ++t) {
    const int sA = t & 3;          // slot holding h(t) / receiving s(t)
    const int sP = (t + 3) & 3;    // slot to re-poison (provably consumed)
    const int sW = (t + 1) & 3;    // slot receiving h(t+1)
    const unsigned short* au = p.u + ((size_t)t * NB + rg * GROW + ar_) * NIN + lk;

    // ======== phase A: z, r, s = r*h ========
    PSTAGE(p.hb + sA * SLOTN + rg * GROW * NHID);        // h(t) poll+stage
    REPOISON(p.sb + sP * SLOTN + rg * GROW * NHID);      // retire s slot t+3
    __syncthreads();                                     // stage ready (only barrier)

    f32x4 az = {0.f, 0.f, 0.f, 0.f};
    f32x4 ar = {0.f, 0.f, 0.f, 0.f};
#pragma unroll
    for (int it = 0; it < 2; ++it) {                     // u-projection (K=64)
      short8v a = ld8(au + it * 32);
      az = __builtin_amdgcn_mfma_f32_16x16x32_bf16(a, ld8(wuz + it * 32), az, 0, 0, 0);
      ar = __builtin_amdgcn_mfma_f32_16x16x32_bf16(a, ld8(wur + it * 32), ar, 0, 0, 0);
    }
#pragma unroll
    for (int it = 0; it < 32; ++it) {                    // full K=1024
      short8v a = LDSA(it);
      az = __builtin_amdgcn_mfma_f32_16x16x32_bf16(a, ld8(wz + it * 32), az, 0, 0, 0);
      ar = __builtin_amdgcn_mfma_f32_16x16x32_bf16(a, ld8(wr + it * 32), ar, 0, 0, 0);
    }
    if (owner) {
#pragma unroll
      for (int i = 0; i < 4; ++i) {
        float z = 1.f / (1.f + __expf(-(az[i] + bzv)));
        float r = 1.f / (1.f + __expf(-(ar[i] + brv)));
        zreg[i] = z;
        cstore16(p.sb + sA * SLOTN + (size_t)(rg * GROW + orow0 + i) * NHID + colN,
                 f2b(r * h_own[i]));
      }
    }

    // ======== phase B: h_tilde, h(t+1) ========
    PSTAGE(p.sb + sA * SLOTN + rg * GROW * NHID);        // s(t) poll+stage
    REPOISON(p.hb + sP * SLOTN + rg * GROW * NHID);      // retire h slot t+3
    __syncthreads();

    f32x4 ac0 = {0.f, 0.f, 0.f, 0.f};                    // 2 chains to break
    f32x4 ac1 = {0.f, 0.f, 0.f, 0.f};                    // MFMA dependency
#pragma unroll
    for (int it = 0; it < 2; ++it) {
      ac0 = __builtin_amdgcn_mfma_f32_16x16x32_bf16(ld8(au + it * 32), ld8(wuh + it * 32), ac0, 0, 0, 0);
    }
#pragma unroll
    for (int it = 0; it < 32; it += 2) {
      ac0 = __builtin_amdgcn_mfma_f32_16x16x32_bf16(LDSA(it), ld8(wh + it * 32), ac0, 0, 0, 0);
      ac1 = __builtin_amdgcn_mfma_f32_16x16x32_bf16(LDSA(it + 1), ld8(wh + (it + 1) * 32), ac1, 0, 0, 0);
    }
    if (owner) {
#pragma unroll
      for (int i = 0; i < 4; ++i) {
        float x = ac0[i] + ac1[i] + bhv;
        float e = __expf(2.f * x);
        float ht = 1.f - 2.f / (e + 1.f);          // tanh, overflow-safe
        float hn = (1.f - zreg[i]) * h_own[i] + zreg[i] * ht;
        h_own[i] = hn;
        cstore16(p.hb + sW * SLOTN + (size_t)(rg * GROW + orow0 + i) * NHID + colN, f2b(hn));
      }
      if (t == TSTEPS - 1) {
#pragma unroll
        for (int i = 0; i < 4; ++i)
          p.h[(size_t)(rg * GROW + orow0 + i) * NHID + colN] = h_own[i];
      }
    }
  }
#undef PSTAGE
#undef REPOISON
#undef LDSA
}

// out[c*R + r] = bf16(in[r*C + c])  (W[k][n] -> WT[n][k])
__global__ void k_transpose_bf16(const float* in, unsigned short* out, int R, int C) {
  int idx = blockIdx.x * 256 + threadIdx.x;
  if (idx < R * C) {
    int r = idx / C, c = idx % C;
    out[(size_t)c * R + r] = f2b(in[idx]);
  }
}

__global__ void k_convert_bf16(const float* in, unsigned short* out, int n) {
  for (int i = blockIdx.x * 256 + threadIdx.x; i < n; i += gridDim.x * 256)
    out[i] = f2b(in[i]);
}

// logits = h_final @ W_hy + b_y ; one block (64 lanes) per batch row
__global__ void k_logits(const float* __restrict__ h, const float* __restrict__ Why,
                         const float* __restrict__ by, float* __restrict__ out) {
  int row = blockIdx.x;
  int lane = threadIdx.x;
  float acc[10];
#pragma unroll
  for (int j = 0; j < 10; ++j) acc[j] = 0.f;
  for (int k = lane; k < NHID; k += 64) {
    float hv = h[row * NHID + k];
#pragma unroll
    for (int j = 0; j < 10; ++j) acc[j] += hv * Why[k * 10 + j];
  }
#pragma unroll
  for (int j = 0; j < 10; ++j)
    for (int off = 32; off; off >>= 1) acc[j] += __shfl_down(acc[j], off);
  if (lane == 0) {
#pragma unroll
    for (int j = 0; j < 10; ++j) out[row * 10 + j] = acc[j] + by[j];
  }
}

extern "C" void kernel_launch(void* const* d_in, const int* in_sizes, int n_in,
                              void* d_out, int out_size, void* d_ws, size_t ws_size,
                              hipStream_t stream) {
  (void)in_sizes; (void)n_in; (void)out_size; (void)ws_size;
  const float* u   = (const float*)d_in[0];
  const float* Wuz = (const float*)d_in[1];
  const float* Whz = (const float*)d_in[2];
  const float* bz  = (const float*)d_in[3];
  const float* Wur = (const float*)d_in[4];
  const float* Whr = (const float*)d_in[5];
  const float* br  = (const float*)d_in[6];
  const float* Wuh = (const float*)d_in[7];
  const float* Whh = (const float*)d_in[8];
  const float* bh  = (const float*)d_in[9];
  const float* Why = (const float*)d_in[10];
  const float* by  = (const float*)d_in[11];

  char* ws = (char*)d_ws;
  size_t off = 0;
  auto alloc = [&](size_t bytes) { char* p = ws + off; off += (bytes + 255) & ~255ull; return p; };
  unsigned short* WhzT = (unsigned short*)alloc((size_t)NHID * NHID * 2);
  unsigned short* WhrT = (unsigned short*)alloc((size_t)NHID * NHID * 2);
  unsigned short* WhhT = (unsigned short*)alloc((size_t)NHID * NHID * 2);
  unsigned short* WuzT = (unsigned short*)alloc((size_t)NHID * NIN * 2);
  unsigned short* WurT = (unsigned short*)alloc((size_t)NHID * NIN * 2);
  unsigned short* WuhT = (unsigned short*)alloc((size_t)NHID * NIN * 2);
  unsigned short* ub   = (unsigned short*)alloc((size_t)TSTEPS * NB * NIN * 2);
  unsigned short* hb   = (unsigned short*)alloc(4ull * SLOTN * 2);
  unsigned short* sb   = (unsigned short*)alloc(4ull * SLOTN * 2);

  float* out = (float*)d_out;
  float* hf  = out + NB * 10;   // h_final region of d_out

  int n1 = NHID * NHID;
  hipLaunchKernelGGL(k_transpose_bf16, dim3((n1 + 255) / 256), dim3(256), 0, stream, Whz, WhzT, NHID, NHID);
  hipLaunchKernelGGL(k_transpose_bf16, dim3((n1 + 255) / 256), dim3(256), 0, stream, Whr, WhrT, NHID, NHID);
  hipLaunchKernelGGL(k_transpose_bf16, dim3((n1 + 255) / 256), dim3(256), 0, stream, Whh, WhhT, NHID, NHID);
  int n2 = NIN * NHID;
  hipLaunchKernelGGL(k_transpose_bf16, dim3((n2 + 255) / 256), dim3(256), 0, stream, Wuz, WuzT, NIN, NHID);
  hipLaunchKernelGGL(k_transpose_bf16, dim3((n2 + 255) / 256), dim3(256), 0, stream, Wur, WurT, NIN, NHID);
  hipLaunchKernelGGL(k_transpose_bf16, dim3((n2 + 255) / 256), dim3(256), 0, stream, Wuh, WuhT, NIN, NHID);
  int n3 = TSTEPS * NB * NIN;
  hipLaunchKernelGGL(k_convert_bf16, dim3(2048), dim3(256), 0, stream, u, ub, n3);
  // Slot init each launch (deterministic under graph replay):
  // hb slot 0 = real h0 = 0; hb slots 1-3 and all sb slots = 0xFFFF poison.
  hipMemsetAsync(hb, 0, (size_t)SLOTN * 2, stream);
  hipMemsetAsync(hb + SLOTN, 0xFF, 3ull * SLOTN * 2, stream);
  hipMemsetAsync(sb, 0xFF, 4ull * SLOTN * 2, stream);

  GruParams p;
  p.u = ub; p.WhzT = WhzT; p.WhrT = WhrT; p.WhhT = WhhT;
  p.WuzT = WuzT; p.WurT = WurT; p.WuhT = WuhT;
  p.bz = bz; p.br = br; p.bh = bh;
  p.h = hf; p.hb = hb; p.sb = sb;
  hipLaunchKernelGGL(gru_main, dim3(NBLK), dim3(NTHR), 0, stream, p);

  hipLaunchKernelGGL(k_logits, dim3(NB), dim3(64), 0, stream, hf, Why, by, out);
}

// Round 14
// 3564.046 us; speedup vs baseline: 4.2236x; 4.2236x over previous
//
#include <hip/hip_runtime.h>

#define NHID 1024
#define NB   128
#define NIN  64
#define TSTEPS 512
#define NBLK 256
#define NTHR 512
#define GROW 8                  // batch rows per group
#define SLOTN (NB * NHID)       // elements per exchange slot

typedef __attribute__((ext_vector_type(8))) short short8v;
typedef __attribute__((ext_vector_type(4))) float f32x4;
typedef __attribute__((ext_vector_type(4))) unsigned u32x4;

__device__ __forceinline__ short8v ld8(const unsigned short* p) {
  return *reinterpret_cast<const short8v*>(p);
}

__device__ __forceinline__ unsigned short f2b(float x) {
  union { float f; unsigned u; } v; v.f = x;
  unsigned r = v.u + 0x7fffu + ((v.u >> 16) & 1u);
  return (unsigned short)(r >> 16);
}

// Unit validity: poison 0xFFFF is unforgeable (|h|,|s| < 1 strictly).
__device__ __forceinline__ bool ok16(u32x4 v) {
  unsigned bad = 0;
#pragma unroll
  for (int i = 0; i < 4; ++i) {
    bad |= (unsigned)((v[i] & 0xFFFFu) == 0xFFFFu);
    bad |= (unsigned)((v[i] >> 16) == 0xFFFFu);
  }
  return bad == 0;
}

struct GruParams {
  const unsigned short* u;                    // [T][B][NIN] bf16
  const unsigned short* WhzT; const unsigned short* WhrT; const unsigned short* WhhT; // [n][k]
  const unsigned short* WuzT; const unsigned short* WurT; const unsigned short* WuhT; // [n][k]
  const float* bz; const float* br; const float* bh;
  float* h;                                   // [B][NHID] f32 — final h only
  unsigned short* hb;                         // [4][16 rg][1024 col][8 row] bf16 h slots
  unsigned short* sb;                         // same layout, r*h slots
};

// Block = 8 batch rows (rg of 16) x 64 hidden cols (cg of 16); 8 waves:
// ct = col-tile (4 x 16 cols), kh = K-half (2 x 512, register-resident weights
// — R13 proved streaming weights is catastrophic). 256 blocks, 1/CU.
// Sync = data itself (poison protocol, R8-proven flavors). NEW vs R8: exchange
// buffers are COLUMN-major [col][8 rows], so each owner lane commits its 4
// values with ONE 8-byte atomic exchange (RMW -> executes at & allocates in
// MALL): 128 store ops/block-phase vs R8's 512, and 16 ops/128B-line vs 64
// (MALL per-line serialization was the residual producer-commit cost).
__global__ __launch_bounds__(NTHR, 2) void gru_main(GruParams p) {
  __shared__ unsigned short stage[GROW * NHID];  // 16KB staged h/s rows (swizzled row-major)
  __shared__ float red[2][4][4][64];             // K-half reduction, component-major

  const int tid  = threadIdx.x;
  const int lane = tid & 63;
  const int w    = tid >> 6;
  const int ct   = w & 3;
  const int kh   = w >> 2;
  const int rg   = blockIdx.x >> 4;   // 16 row groups (8 rows each)
  const int cg   = blockIdx.x & 15;   // 16 col groups (64 cols each)
  const int lr   = lane & 15;
  const int ar_  = lr & 7;            // aliased A-row for 8-row tiles
  const int lk   = (lane >> 4) * 8;

  const int colN = cg * 64 + ct * 16 + lr;
  const unsigned short* wz  = p.WhzT + (size_t)colN * NHID + kh * 512 + lk;
  const unsigned short* wr  = p.WhrT + (size_t)colN * NHID + kh * 512 + lk;
  const unsigned short* wh  = p.WhhT + (size_t)colN * NHID + kh * 512 + lk;
  const unsigned short* wuz = p.WuzT + colN * NIN + lk;
  const unsigned short* wur = p.WurT + colN * NIN + lk;
  const unsigned short* wuh = p.WuhT + colN * NIN + lk;

  const int orow0 = (lane >> 4) * 4;  // output row base; only orow0<8 is real
  const bool owner = orow0 < GROW;    // lanes 0..31 of !kh waves
  const float bzv = p.bz[colN];
  const float brv = p.br[colN];
  const float bhv = p.bh[colN];

  const u32x4 poisonv = {0xFFFFFFFFu, 0xFFFFFFFFu, 0xFFFFFFFFu, 0xFFFFFFFFu};

  // Loop-invariant recurrent-weight B-fragments (static indexing only — rule #20).
  short8v Wz[16], Wr[16], Wh[16];
#pragma unroll
  for (int it = 0; it < 16; ++it) {
    Wz[it] = ld8(wz + it * 32);
    Wr[it] = ld8(wr + it * 32);
    Wh[it] = ld8(wh + it * 32);
  }

  float h_own[4] = {0.f, 0.f, 0.f, 0.f};
  float zreg[4];

  // Poll-stage from col-major slice: unit = col (16B = 8 rows). 512 thr x 2
  // units, coalesced 16B sc0sc1 polls until non-poison (each 8B half is one
  // producer's atomic -> tearing-safe), then transpose-scatter into swizzled
  // row-major LDS (16 conflict-free ds_write_b16/thread, off critical path).
#define PSTAGE(SRC)                                                              \
  {                                                                              \
    int j0 = tid, j1 = tid + NTHR;                                               \
    const unsigned short* g0 = (SRC) + j0 * 8;                                   \
    const unsigned short* g1 = (SRC) + j1 * 8;                                   \
    u32x4 v0 = poisonv, v1 = poisonv;                                            \
    bool k0 = false, k1 = false;                                                 \
    for (int spin = 0; spin < (1 << 13); ++spin) {                               \
      if (!k0) asm volatile("global_load_dwordx4 %0, %1, off sc0 sc1"            \
                            : "=v"(v0) : "v"(g0) : "memory");                    \
      if (!k1) asm volatile("global_load_dwordx4 %0, %1, off sc0 sc1"            \
                            : "=v"(v1) : "v"(g1) : "memory");                    \
      asm volatile("s_waitcnt vmcnt(0)" ::: "memory");                           \
      k0 = k0 || ok16(v0);                                                       \
      k1 = k1 || ok16(v1);                                                       \
      if (k0 && k1) break;                                                       \
    }                                                                            \
    _Pragma("unroll")                                                            \
    for (int r = 0; r < 8; ++r) {                                                \
      unsigned short a0 = (unsigned short)(v0[r >> 1] >> ((r & 1) * 16));        \
      unsigned short a1 = (unsigned short)(v1[r >> 1] >> ((r & 1) * 16));        \
      *(unsigned short*)((char*)stage + ((r * 2048) | ((j0 * 2) ^ (r << 4)))) = a0; \
      *(unsigned short*)((char*)stage + ((r * 2048) | ((j1 * 2) ^ (r << 4)))) = a1; \
    }                                                                            \
  }

  // Re-poison own 64-col slice of a consumed slot: col-major makes it a single
  // contiguous 1KB region -> 64 x 16B coalesced stores (R8-proven flavor).
#define REPOISON(SLOTSLICE)                                                      \
  if (tid < 64) {                                                                \
    void* rp = (char*)(SLOTSLICE) + cg * 1024 + tid * 16;                        \
    asm volatile("global_store_dwordx4 %0, %1, off sc0 sc1"                      \
                 :: "v"(rp), "v"(poisonv) : "memory");                           \
  }

#define LDSA(IT)                                                                \
  (*(const short8v*)((const char*)stage +                                       \
     ((ar_ * 2048) | ((((kh * 512 + (IT) * 32 + lk) * 2)) ^ (ar_ << 4)))))

  for (int t = 0; t < TSTEPS; ++t) {
    const int sA = t & 3;          // slot holding h(t) / receiving s(t)
    const int sP = (t + 3) & 3;    // slot to re-poison (provably consumed)
    const int sW = (t + 1) & 3;    // slot receiving h(t+1)
    const unsigned short* au = p.u + ((size_t)t * NB + rg * GROW + ar_) * NIN + lk;
    unsigned short* hbR = p.hb + (size_t)sA * SLOTN + rg * GROW * NHID;
    unsigned short* sbR = p.sb + (size_t)sA * SLOTN + rg * GROW * NHID;

    // ======== phase A: z, r, s = r*h ========
    f32x4 az = {0.f, 0.f, 0.f, 0.f};
    f32x4 ar = {0.f, 0.f, 0.f, 0.f};
    if (kh) {        // u-projection overlaps the data poll
#pragma unroll
      for (int it = 0; it < 2; ++it) {
        short8v a = ld8(au + it * 32);
        az = __builtin_amdgcn_mfma_f32_16x16x32_bf16(a, ld8(wuz + it * 32), az, 0, 0, 0);
        ar = __builtin_amdgcn_mfma_f32_16x16x32_bf16(a, ld8(wur + it * 32), ar, 0, 0, 0);
      }
    }
    PSTAGE(hbR);                                         // h(t) poll+stage
    REPOISON(p.sb + (size_t)sP * SLOTN + rg * GROW * NHID);  // retire s slot t+3
    asm volatile("s_waitcnt vmcnt(0)" ::: "memory");     // re-poison at MALL
    __syncthreads();                                     // ... before any data store

#pragma unroll
    for (int it = 0; it < 16; ++it) {
      short8v a = LDSA(it);
      az = __builtin_amdgcn_mfma_f32_16x16x32_bf16(a, Wz[it], az, 0, 0, 0);
      ar = __builtin_amdgcn_mfma_f32_16x16x32_bf16(a, Wr[it], ar, 0, 0, 0);
    }
    if (kh) {
#pragma unroll
      for (int j = 0; j < 4; ++j) { red[0][ct][j][lane] = az[j]; red[1][ct][j][lane] = ar[j]; }
    }
    __syncthreads();
    if (!kh && owner) {
      unsigned long long sd = 0;
#pragma unroll
      for (int i = 0; i < 4; ++i) {
        float z = 1.f / (1.f + __expf(-(az[i] + red[0][ct][i][lane] + bzv)));
        float r = 1.f / (1.f + __expf(-(ar[i] + red[1][ct][i][lane] + brv)));
        zreg[i] = z;
        sd |= (unsigned long long)f2b(r * h_own[i]) << (16 * i);
      }
      // ONE 8B atomic exchange commits rows orow0..+3 of col colN (MALL-resident)
      (void)__hip_atomic_exchange((unsigned long long*)(sbR + colN * 8 + orow0),
                                  sd, __ATOMIC_RELAXED, __HIP_MEMORY_SCOPE_AGENT);
    }

    // ======== phase B: h_tilde, h(t+1) ========
    f32x4 ac = {0.f, 0.f, 0.f, 0.f};
    if (kh) {
#pragma unroll
      for (int it = 0; it < 2; ++it) {
        ac = __builtin_amdgcn_mfma_f32_16x16x32_bf16(ld8(au + it * 32), ld8(wuh + it * 32), ac, 0, 0, 0);
      }
    }
    PSTAGE(sbR);                                         // s(t) poll+stage
    REPOISON(p.hb + (size_t)sP * SLOTN + rg * GROW * NHID);  // retire h slot t+3
    asm volatile("s_waitcnt vmcnt(0)" ::: "memory");
    __syncthreads();

#pragma unroll
    for (int it = 0; it < 16; ++it) {
      ac = __builtin_amdgcn_mfma_f32_16x16x32_bf16(LDSA(it), Wh[it], ac, 0, 0, 0);
    }
    if (kh) {
#pragma unroll
      for (int j = 0; j < 4; ++j) red[0][ct][j][lane] = ac[j];
    }
    __syncthreads();
    if (!kh && owner) {
      unsigned long long hd = 0;
#pragma unroll
      for (int i = 0; i < 4; ++i) {
        float x = ac[i] + red[0][ct][i][lane] + bhv;
        float e = __expf(2.f * x);
        float ht = 1.f - 2.f / (e + 1.f);          // tanh, overflow-safe
        float hn = (1.f - zreg[i]) * h_own[i] + zreg[i] * ht;
        h_own[i] = hn;
        hd |= (unsigned long long)f2b(hn) << (16 * i);
      }
      unsigned short* hbW = p.hb + (size_t)sW * SLOTN + rg * GROW * NHID;
      (void)__hip_atomic_exchange((unsigned long long*)(hbW + colN * 8 + orow0),
                                  hd, __ATOMIC_RELAXED, __HIP_MEMORY_SCOPE_AGENT);
      if (t == TSTEPS - 1) {
#pragma unroll
        for (int i = 0; i < 4; ++i)
          p.h[(size_t)(rg * GROW + orow0 + i) * NHID + colN] = h_own[i];
      }
    }
  }
#undef PSTAGE
#undef REPOISON
#undef LDSA
}

// out[c*R + r] = bf16(in[r*C + c])  (W[k][n] -> WT[n][k])
__global__ void k_transpose_bf16(const float* in, unsigned short* out, int R, int C) {
  int idx = blockIdx.x * 256 + threadIdx.x;
  if (idx < R * C) {
    int r = idx / C, c = idx % C;
    out[(size_t)c * R + r] = f2b(in[idx]);
  }
}

__global__ void k_convert_bf16(const float* in, unsigned short* out, int n) {
  for (int i = blockIdx.x * 256 + threadIdx.x; i < n; i += gridDim.x * 256)
    out[i] = f2b(in[i]);
}

// logits = h_final @ W_hy + b_y ; one block (64 lanes) per batch row
__global__ void k_logits(const float* __restrict__ h, const float* __restrict__ Why,
                         const float* __restrict__ by, float* __restrict__ out) {
  int row = blockIdx.x;
  int lane = threadIdx.x;
  float acc[10];
#pragma unroll
  for (int j = 0; j < 10; ++j) acc[j] = 0.f;
  for (int k = lane; k < NHID; k += 64) {
    float hv = h[row * NHID + k];
#pragma unroll
    for (int j = 0; j < 10; ++j) acc[j] += hv * Why[k * 10 + j];
  }
#pragma unroll
  for (int j = 0; j < 10; ++j)
    for (int off = 32; off; off >>= 1) acc[j] += __shfl_down(acc[j], off);
  if (lane == 0) {
#pragma unroll
    for (int j = 0; j < 10; ++j) out[row * 10 + j] = acc[j] + by[j];
  }
}

extern "C" void kernel_launch(void* const* d_in, const int* in_sizes, int n_in,
                              void* d_out, int out_size, void* d_ws, size_t ws_size,
                              hipStream_t stream) {
  (void)in_sizes; (void)n_in; (void)out_size; (void)ws_size;
  const float* u   = (const float*)d_in[0];
  const float* Wuz = (const float*)d_in[1];
  const float* Whz = (const float*)d_in[2];
  const float* bz  = (const float*)d_in[3];
  const float* Wur = (const float*)d_in[4];
  const float* Whr = (const float*)d_in[5];
  const float* br  = (const float*)d_in[6];
  const float* Wuh = (const float*)d_in[7];
  const float* Whh = (const float*)d_in[8];
  const float* bh  = (const float*)d_in[9];
  const float* Why = (const float*)d_in[10];
  const float* by  = (const float*)d_in[11];

  char* ws = (char*)d_ws;
  size_t off = 0;
  auto alloc = [&](size_t bytes) { char* p = ws + off; off += (bytes + 255) & ~255ull; return p; };
  unsigned short* WhzT = (unsigned short*)alloc((size_t)NHID * NHID * 2);
  unsigned short* WhrT = (unsigned short*)alloc((size_t)NHID * NHID * 2);
  unsigned short* WhhT = (unsigned short*)alloc((size_t)NHID * NHID * 2);
  unsigned short* WuzT = (unsigned short*)alloc((size_t)NHID * NIN * 2);
  unsigned short* WurT = (unsigned short*)alloc((size_t)NHID * NIN * 2);
  unsigned short* WuhT = (unsigned short*)alloc((size_t)NHID * NIN * 2);
  unsigned short* ub   = (unsigned short*)alloc((size_t)TSTEPS * NB * NIN * 2);
  unsigned short* hb   = (unsigned short*)alloc(4ull * SLOTN * 2);
  unsigned short* sb   = (unsigned short*)alloc(4ull * SLOTN * 2);

  float* out = (float*)d_out;
  float* hf  = out + NB * 10;   // h_final region of d_out

  int n1 = NHID * NHID;
  hipLaunchKernelGGL(k_transpose_bf16, dim3((n1 + 255) / 256), dim3(256), 0, stream, Whz, WhzT, NHID, NHID);
  hipLaunchKernelGGL(k_transpose_bf16, dim3((n1 + 255) / 256), dim3(256), 0, stream, Whr, WhrT, NHID, NHID);
  hipLaunchKernelGGL(k_transpose_bf16, dim3((n1 + 255) / 256), dim3(256), 0, stream, Whh, WhhT, NHID, NHID);
  int n2 = NIN * NHID;
  hipLaunchKernelGGL(k_transpose_bf16, dim3((n2 + 255) / 256), dim3(256), 0, stream, Wuz, WuzT, NIN, NHID);
  hipLaunchKernelGGL(k_transpose_bf16, dim3((n2 + 255) / 256), dim3(256), 0, stream, Wur, WurT, NIN, NHID);
  hipLaunchKernelGGL(k_transpose_bf16, dim3((n2 + 255) / 256), dim3(256), 0, stream, Wuh, WuhT, NIN, NHID);
  int n3 = TSTEPS * NB * NIN;
  hipLaunchKernelGGL(k_convert_bf16, dim3(2048), dim3(256), 0, stream, u, ub, n3);
  // Slot init each launch (deterministic under graph replay):
  // hb slot 0 = real h0 = 0; hb slots 1-3 and all sb slots = 0xFFFF poison.
  hipMemsetAsync(hb, 0, (size_t)SLOTN * 2, stream);
  hipMemsetAsync(hb + SLOTN, 0xFF, 3ull * SLOTN * 2, stream);
  hipMemsetAsync(sb, 0xFF, 4ull * SLOTN * 2, stream);

  GruParams p;
  p.u = ub; p.WhzT = WhzT; p.WhrT = WhrT; p.WhhT = WhhT;
  p.WuzT = WuzT; p.WurT = WurT; p.WuhT = WuhT;
  p.bz = bz; p.br = br; p.bh = bh;
  p.h = hf; p.hb = hb; p.sb = sb;
  hipLaunchKernelGGL(gru_main, dim3(NBLK), dim3(NTHR), 0, stream, p);

  hipLaunchKernelGGL(k_logits, dim3(NB), dim3(64), 0, stream, hf, Why, by, out);
}